// Round 2
// 361.469 us; speedup vs baseline: 1.1266x; 1.1266x over previous
//
#include <hip/hip_runtime.h>
#include <stdint.h>

// LocalMHA on MI355X (gfx950).
// Pipeline: convert_x (f32->bf16) + transpose_w (LDS-tiled) ->
//           GEMM1 (qkv proj, 256x256 8-phase MFMA bf16, fused RoPE epilogue) ->
//           windowed attention (MFMA bf16, sliding window 129, no-max softmax) ->
//           GEMM2 (out proj, same 8-phase GEMM, fp32 store)
// GEMMs use the verified 256^2 8-phase schedule: BK=64 double-buffered LDS
// ([16x32] bf16 subtiles -> ds_read is base+lane*16, conflict-free by
// construction; staging SOURCE is lane-permuted so the linear global_load_lds
// dest yields that layout), counted s_waitcnt vmcnt(6) (never 0 in main loop),
// raw s_barrier, setprio(1) around each 16-MFMA cluster.

typedef __attribute__((ext_vector_type(8))) short bfrag;  // 8 bf16 in 4 VGPRs
typedef __attribute__((ext_vector_type(4))) float f4;

#define MFMA_BF16(a, b, c) __builtin_amdgcn_mfma_f32_16x16x32_bf16((a), (b), (c), 0, 0, 0)

static __device__ __forceinline__ short f2bf(float f) {  // round-to-nearest-even
  unsigned u = __builtin_bit_cast(unsigned, f);
  u = (u + 0x7fffu + ((u >> 16) & 1u)) >> 16;
  return (short)u;
}
static __device__ __forceinline__ float bf2f(short s) {
  unsigned u = ((unsigned)(unsigned short)s) << 16;
  return __builtin_bit_cast(float, u);
}

typedef __attribute__((address_space(3))) unsigned lds_u;
typedef __attribute__((address_space(1))) unsigned gbl_u;

// global -> LDS direct DMA, 16B/lane. LDS dest = wave-uniform base + lane*16.
static __device__ __forceinline__ void gl_lds16(const void* g, const void* lds) {
  unsigned loff = (unsigned)__builtin_amdgcn_readfirstlane((int)(uintptr_t)lds);
  __builtin_amdgcn_global_load_lds((gbl_u*)(uintptr_t)g, (lds_u*)(uintptr_t)loff, 16, 0, 0);
}

// ---------------------------------------------------------------------------
// Kernel 1a: x (16384x1024 f32) -> xb bf16, vectorized 8 elems/thread.
// ---------------------------------------------------------------------------
__global__ __launch_bounds__(256) void convert_x(const float* __restrict__ x,
                                                 short* __restrict__ xb) {
  int idx = blockIdx.x * 256 + threadIdx.x;  // 2M threads x 8 elems
  size_t base = (size_t)idx * 8;
  float4 a = *(const float4*)(x + base);
  float4 b = *(const float4*)(x + base + 4);
  bfrag o;
  o[0] = f2bf(a.x); o[1] = f2bf(a.y); o[2] = f2bf(a.z); o[3] = f2bf(a.w);
  o[4] = f2bf(b.x); o[5] = f2bf(b.y); o[6] = f2bf(b.z); o[7] = f2bf(b.w);
  *(bfrag*)(xb + base) = o;
}

// ---------------------------------------------------------------------------
// Kernel 1b: LDS-tiled 64x64 transpose+convert of W_qkv [1024,3072] and
// W_out [1024,1024] into N-major bf16 (coalesced reads AND writes).
// grid (16, 64): y<48 -> wqkv tile, else wout tile (y-48).
// ---------------------------------------------------------------------------
__global__ __launch_bounds__(256) void transpose_w(
    const float* __restrict__ wqkv, const float* __restrict__ wout,
    short* __restrict__ wqkvT, short* __restrict__ woutT) {
  __shared__ short t[64][72];
  const int tid = threadIdx.x;
  const int kt = blockIdx.x, yt = blockIdx.y;
  const float* src; short* dst; int N, nt;
  if (yt < 48) { src = wqkv; dst = wqkvT; N = 3072; nt = yt; }
  else         { src = wout; dst = woutT; N = 1024; nt = yt - 48; }
  const int k0 = kt * 64, n0 = nt * 64;
#pragma unroll
  for (int i = 0; i < 4; ++i) {
    int r = i * 16 + (tid >> 4);  // k-local
    int c = (tid & 15) * 4;       // n-local
    float4 v = *(const float4*)(src + (size_t)(k0 + r) * N + n0 + c);
    t[c + 0][r] = f2bf(v.x);
    t[c + 1][r] = f2bf(v.y);
    t[c + 2][r] = f2bf(v.z);
    t[c + 3][r] = f2bf(v.w);
  }
  __syncthreads();
#pragma unroll
  for (int i = 0; i < 2; ++i) {
    int c = tid + i * 256;
    int n = c >> 3, k8 = (c & 7) * 8;
    *(bfrag*)(dst + (size_t)(n0 + n) * 1024 + k0 + k8) = *(const bfrag*)&t[n][k8];
  }
}

// ---------------------------------------------------------------------------
// 256x256 8-phase bf16 GEMM: C[M,N] = A[M,1024] * Bt[N,1024]^T.
// 512 threads = 8 waves (2 M-waves x 4 N-waves); each wave owns 128x64.
// BK=64 as two 32-wide k-planes; LDS 128 KiB (2 dbuf x 2 planes x A,B).
// Plane layout: 16 subtiles of [16 rows][32 k] bf16 (1024 B contiguous).
// Within a subtile, 16B granule g holds logical (row=g&15, kgrp=g>>4), so the
// MFMA frag read (lane: row=l15, kgrp=quad) is exactly base+lane*16 -> linear,
// bank-conflict-free. global_load_lds dest is linear; the SOURCE address is
// lane-permuted to produce this layout (srow=lane&15, scg=lane>>4).
// Schedule per K-tile (4 phases = (ks,mh)): ds_read 8x b128, 1 plane prefetch
// (2 loads), vmcnt(6) at phases 1,3, barrier, lgkmcnt(0), 16 MFMA in
// setprio(1), barrier. 3 planes stay in flight across barriers.
// MODE 0: RoPE+scale epilogue scatters into q/k/v [B,H,N,64] bf16.
// MODE 1: plain fp32 C store (output projection).
// ---------------------------------------------------------------------------
#define VM6 asm volatile("s_waitcnt vmcnt(6)" ::: "memory")
#define VM4 asm volatile("s_waitcnt vmcnt(4)" ::: "memory")
#define VM0 asm volatile("s_waitcnt vmcnt(0)" ::: "memory")
#define VNOP ((void)0)

// stage one 16 KiB k-plane (2 x global_load_lds per thread)
#define ST_A(buf, ks, kk)                                                          \
  do {                                                                             \
    gl_lds16(aS0 + (ks) * 32 + (kk), ldsA + (buf) * 32768 + (ks) * 16384 + stA);   \
    gl_lds16(aS1 + (ks) * 32 + (kk),                                               \
             ldsA + (buf) * 32768 + (ks) * 16384 + 8192 + stA);                    \
  } while (0)
#define ST_B(buf, ks, kk)                                                          \
  do {                                                                             \
    gl_lds16(bS0 + (ks) * 32 + (kk), ldsB + (buf) * 32768 + (ks) * 16384 + stA);   \
    gl_lds16(bS1 + (ks) * 32 + (kk),                                               \
             ldsB + (buf) * 32768 + (ks) * 16384 + 8192 + stA);                    \
  } while (0)

#define MM4(mi, a)                                 \
  acc[mi][0] = MFMA_BF16(a, b0, acc[mi][0]);       \
  acc[mi][1] = MFMA_BF16(a, b1, acc[mi][1]);       \
  acc[mi][2] = MFMA_BF16(a, b2, acc[mi][2]);       \
  acc[mi][3] = MFMA_BF16(a, b3, acc[mi][3])

#define PHASE(buf, ks, mh, STAGE, WAIT)                                            \
  {                                                                                \
    const char* pA_ = ldsA + (buf) * 32768 + (ks) * 16384 + (mh) * 4096 + aRd;     \
    const char* pB_ = ldsB + (buf) * 32768 + (ks) * 16384 + bRd;                   \
    bfrag a0 = *(const bfrag*)(pA_);                                               \
    bfrag a1 = *(const bfrag*)(pA_ + 1024);                                        \
    bfrag a2 = *(const bfrag*)(pA_ + 2048);                                        \
    bfrag a3 = *(const bfrag*)(pA_ + 3072);                                        \
    bfrag b0 = *(const bfrag*)(pB_);                                               \
    bfrag b1 = *(const bfrag*)(pB_ + 1024);                                        \
    bfrag b2 = *(const bfrag*)(pB_ + 2048);                                        \
    bfrag b3 = *(const bfrag*)(pB_ + 3072);                                        \
    STAGE;                                                                         \
    WAIT;                                                                          \
    __builtin_amdgcn_s_barrier();                                                  \
    asm volatile("s_waitcnt lgkmcnt(0)" ::: "memory");                             \
    __builtin_amdgcn_sched_barrier(0);                                             \
    __builtin_amdgcn_s_setprio(1);                                                 \
    MM4((mh) * 4 + 0, a0);                                                         \
    MM4((mh) * 4 + 1, a1);                                                         \
    MM4((mh) * 4 + 2, a2);                                                         \
    MM4((mh) * 4 + 3, a3);                                                         \
    __builtin_amdgcn_s_setprio(0);                                                 \
    __builtin_amdgcn_s_barrier();                                                  \
  }

template <int MODE, int NBX>
__global__ __launch_bounds__(512, 2) void gemm256(
    const short* __restrict__ A, const short* __restrict__ Bt, float* __restrict__ C,
    short* __restrict__ oq, short* __restrict__ ok, short* __restrict__ ov) {
  __shared__ __align__(1024) char lds[131072];  // A: [0,64K) B: [64K,128K)
  char* const ldsA = lds;
  char* const ldsB = lds + 65536;

  const int tid = threadIdx.x, lane = tid & 63, wv = tid >> 6;
  const int wr = wv >> 2, wc = wv & 3;
  const int l15 = lane & 15, quad = lane >> 4;

  // XCD-aware bijective swizzle (nwg = NBX*64, divisible by 8).
  const int nwg = NBX * 64;
  const int bid = (int)blockIdx.x;
  const int wgid = (bid & 7) * (nwg >> 3) + (bid >> 3);
  const int bx = wgid % NBX, by = wgid / NBX;

  const short* Ab = A + (size_t)by * 256 * 1024;
  const short* Bb = Bt + (size_t)bx * 256 * 1024;

  // Staging source: DMA lane l writes LDS granule l of the wave's subtile;
  // granule l must hold logical (row = l&15, kgrp = l>>4).
  const int srow = lane & 15, scg = lane >> 4;
  const short* aS0 = Ab + (size_t)(wv * 16 + srow) * 1024 + scg * 8;
  const short* aS1 = Ab + (size_t)((8 + wv) * 16 + srow) * 1024 + scg * 8;
  const short* bS0 = Bb + (size_t)(wv * 16 + srow) * 1024 + scg * 8;
  const short* bS1 = Bb + (size_t)((8 + wv) * 16 + srow) * 1024 + scg * 8;
  const int stA = wv * 1024;  // wave-uniform LDS dest offset (call0; call1 +8192)

  // ds_read: linear base + lane*16 within each subtile.
  const int rdoff = lane * 16;
  const int aRd = wr * 8192 + rdoff;  // + mh*4096 + m*1024
  const int bRd = wc * 4096 + rdoff;  // + n*1024

  f4 acc[8][4];
#pragma unroll
  for (int i = 0; i < 8; ++i)
#pragma unroll
    for (int j = 0; j < 4; ++j) acc[i][j] = (f4)0.f;

  // ---- prologue: tile0 all 4 planes + tile1 A-ks0; wait oldest 2 planes ----
  ST_A(0, 0, 0); ST_B(0, 0, 0); ST_A(0, 1, 0); ST_B(0, 1, 0); ST_A(1, 0, 64);
  VM6;
  __builtin_amdgcn_s_barrier();

  // ---- main loop: tile pairs (t,buf0),(t+1,buf1), t = 0..12 ----
#pragma unroll 1
  for (int t = 0; t < 14; t += 2) {
    const int kk1 = t * 64 + 64, kk2 = t * 64 + 128, kk3 = t * 64 + 192;
    PHASE(0, 0, 0, ST_B(1, 0, kk1), VNOP);  // stage (t+1,B0)
    PHASE(0, 0, 1, ST_A(1, 1, kk1), VM6);   // stage (t+1,A1); covers (t,A1/B1)
    PHASE(0, 1, 0, ST_B(1, 1, kk1), VNOP);  // stage (t+1,B1)
    PHASE(0, 1, 1, ST_A(0, 0, kk2), VM6);   // stage (t+2,A0); covers (t+1,A0/B0)
    PHASE(1, 0, 0, ST_B(0, 0, kk2), VNOP);
    PHASE(1, 0, 1, ST_A(0, 1, kk2), VM6);
    PHASE(1, 1, 0, ST_B(0, 1, kk2), VNOP);
    PHASE(1, 1, 1, ST_A(1, 0, kk3), VM6);
  }

  // ---- drain: tile 14 (buf0) stages tile 15 remainder; tile 15 (buf1) ----
  PHASE(0, 0, 0, ST_B(1, 0, 960), VNOP);
  PHASE(0, 0, 1, ST_A(1, 1, 960), VM6);
  PHASE(0, 1, 0, ST_B(1, 1, 960), VNOP);
  PHASE(0, 1, 1, VNOP, VM4);  // covers (15,A0/B0); leaves (15,A1/B1) in flight
  PHASE(1, 0, 0, VNOP, VNOP);
  PHASE(1, 0, 1, VNOP, VM0);  // final drain for (15,A1/B1)
  PHASE(1, 1, 0, VNOP, VNOP);
  PHASE(1, 1, 1, VNOP, VNOP);

  // ---- epilogue: C/D layout col=lane&15, row=quad*4+reg ----
  if constexpr (MODE == 0) {
    const int n64 = bx * 256 + wc * 64;  // 64-aligned -> one (part, head)
    const int part = n64 >> 10;          // 0=q 1=k 2=v (wave-uniform)
    const int head = (n64 & 1023) >> 6;
    short* o = (part == 0) ? oq : (part == 1) ? ok : ov;
    const float f0 = exp2f((float)l15 * -0.41524101186f);  // 10000^(-d/32)
    const float f1 = exp2f((float)(16 + l15) * -0.41524101186f);
#pragma unroll
    for (int i = 0; i < 8; ++i)
#pragma unroll
      for (int r = 0; r < 4; ++r) {
        const int m = by * 256 + wr * 128 + i * 16 + quad * 4 + r;
        const int b = m >> 12, p = m & 4095;
        short* row = o + ((size_t)(b * 16 + head) * 4096 + p) * 64;
        if (part == 2) {
#pragma unroll
          for (int j = 0; j < 4; ++j) row[j * 16 + l15] = f2bf(acc[i][j][r]);
        } else {
#pragma unroll
          for (int j = 0; j < 2; ++j) {
            float av = acc[i][j][r], bv2 = acc[i][j + 2][r];
            float sn, cs;
            __sincosf((float)p * (j ? f1 : f0), &sn, &cs);
            float ra = av * cs - bv2 * sn;
            float rb = bv2 * cs + av * sn;
            if (part == 0) { ra *= 0.125f; rb *= 0.125f; }
            row[j * 16 + l15] = f2bf(ra);
            row[32 + j * 16 + l15] = f2bf(rb);
          }
        }
      }
  } else {
#pragma unroll
    for (int i = 0; i < 8; ++i)
#pragma unroll
      for (int j = 0; j < 4; ++j)
#pragma unroll
        for (int r = 0; r < 4; ++r) {
          int m = by * 256 + wr * 128 + i * 16 + quad * 4 + r;
          int n = bx * 256 + wc * 64 + j * 16 + l15;
          C[(size_t)m * 1024 + n] = acc[i][j][r];
        }
  }
}

// ---------------------------------------------------------------------------
// Kernel 3: windowed attention. One block (256 thr, 4 waves) per (b,h,w).
// Keys for window w: abs positions [w*128-128, w*128+128). Valid keys for
// query i (window-local): jj in [i, i+128], plus jj>=128 when w==0.
// Softmax without max-subtraction: q pre-scaled by 0.125 -> |sim| << 88.
// ---------------------------------------------------------------------------
__global__ __launch_bounds__(256) void attn_kernel(
    const short* __restrict__ qb, const short* __restrict__ kb,
    const short* __restrict__ vb, short* __restrict__ ob) {
  constexpr int KST = 72, VST = 264, PST = 136;
  __shared__ __align__(16) short smem[18432 + 16896];  // 69 KB -> 2 blocks/CU
  short* Ks = smem;          // 256 x KST; aliased by P (128 x PST)
  short* Pl = smem;
  short* Vt = smem + 18432;  // 64 x VST (V transposed)

  const int bid = blockIdx.x;
  const int w = bid & 31, bh = bid >> 5;
  const int tid = threadIdx.x, lane = tid & 63, wv = tid >> 6;
  const int l15 = lane & 15, quad = lane >> 4;
  const size_t kvbase = (size_t)bh * (4096 * 64);
  const int pk0 = w * 128 - 128;

  // ---- Q A-frags straight from global (issued early to overlap staging) ----
  const int i0 = wv * 32;  // this wave's 32 query rows
  const short* qbase = qb + kvbase + (size_t)(w * 128) * 64;
  bfrag aq[2][2];
#pragma unroll
  for (int rt = 0; rt < 2; ++rt)
#pragma unroll
    for (int ks = 0; ks < 2; ++ks)
      aq[rt][ks] = *(const bfrag*)(qbase + (size_t)(i0 + rt * 16 + l15) * 64 + ks * 32 + quad * 8);

  // ---- stage K (row layout) and V^T ----
#pragma unroll
  for (int i = 0; i < 8; ++i) {
    int c = tid + i * 256;  // 2048 x 16B chunks
    int row = c >> 3;       // key index jj 0..255
    int d0 = (c & 7) * 8;
    int pk = pk0 + row;
    if (pk < 0) pk = 0;  // OOB keys are masked; clamp to stay in bounds
    const size_t src = kvbase + (size_t)pk * 64 + d0;
    bfrag kvv = *(const bfrag*)(kb + src);
    *(bfrag*)&Ks[row * KST + d0] = kvv;
    bfrag vvv = *(const bfrag*)(vb + src);
#pragma unroll
    for (int j = 0; j < 8; ++j) Vt[(d0 + j) * VST + row] = vvv[j];
  }
  __syncthreads();

  // ---- sim = Q K^T : 2 row-tiles x 16 col-tiles ----
  f4 sim[2][16];
#pragma unroll
  for (int rt = 0; rt < 2; ++rt)
#pragma unroll
    for (int ct = 0; ct < 16; ++ct) sim[rt][ct] = (f4)0.f;

#pragma unroll
  for (int ct = 0; ct < 16; ++ct) {
    bfrag bk0 = *(const bfrag*)&Ks[(ct * 16 + l15) * KST + quad * 8];
    bfrag bk1 = *(const bfrag*)&Ks[(ct * 16 + l15) * KST + 32 + quad * 8];
#pragma unroll
    for (int rt = 0; rt < 2; ++rt) {
      sim[rt][ct] = MFMA_BF16(aq[rt][0], bk0, sim[rt][ct]);
      sim[rt][ct] = MFMA_BF16(aq[rt][1], bk1, sim[rt][ct]);
    }
  }
  __syncthreads();  // all K reads done; Ks region free for P

  // ---- masked softmax, no max-subtraction (values bounded; fp32 exp safe) ----
  float linv[2][4];
#pragma unroll
  for (int rt = 0; rt < 2; ++rt)
#pragma unroll
    for (int r = 0; r < 4; ++r) {
      const int iloc = i0 + rt * 16 + quad * 4 + r;
      float sum = 0.f;
#pragma unroll
      for (int ct = 0; ct < 16; ++ct) {
        int jj = ct * 16 + l15;
        bool valid = (jj >= iloc) && (jj <= iloc + 128) && ((w > 0) || (jj >= 128));
        float pv = valid ? __expf(sim[rt][ct][r]) : 0.f;
        sim[rt][ct][r] = pv;
        sum += pv;
      }
#pragma unroll
      for (int off = 1; off < 16; off <<= 1) sum += __shfl_xor(sum, off);
      linv[rt][r] = 1.f / sum;
    }

  // ---- out = P V in two 128-key passes; P rows are wave-private in LDS ----
  f4 oacc[2][4];
#pragma unroll
  for (int rt = 0; rt < 2; ++rt)
#pragma unroll
    for (int ctd = 0; ctd < 4; ++ctd) oacc[rt][ctd] = (f4)0.f;

#pragma unroll
  for (int pass = 0; pass < 2; ++pass) {
#pragma unroll
    for (int rt = 0; rt < 2; ++rt)
#pragma unroll
      for (int ct = 0; ct < 8; ++ct) {
        int ctg = pass * 8 + ct;
#pragma unroll
        for (int r = 0; r < 4; ++r)
          Pl[(i0 + rt * 16 + quad * 4 + r) * PST + ct * 16 + l15] = f2bf(sim[rt][ctg][r]);
      }
    // same-wave DS ordering gives write->read visibility; rows disjoint per wave
#pragma unroll
    for (int ks = 0; ks < 4; ++ks) {
      bfrag ap[2];
#pragma unroll
      for (int rt = 0; rt < 2; ++rt)
        ap[rt] = *(const bfrag*)&Pl[(i0 + rt * 16 + l15) * PST + ks * 32 + quad * 8];
#pragma unroll
      for (int ctd = 0; ctd < 4; ++ctd) {
        bfrag bv = *(const bfrag*)&Vt[(ctd * 16 + l15) * VST + pass * 128 + ks * 32 + quad * 8];
#pragma unroll
        for (int rt = 0; rt < 2; ++rt) oacc[rt][ctd] = MFMA_BF16(ap[rt], bv, oacc[rt][ctd]);
      }
    }
  }

  // ---- epilogue: normalize and write [b][p][h*64+d] bf16 ----
  const int b = bh >> 4, h = bh & 15;
  short* obase = ob + ((size_t)b * 4096 + w * 128) * 1024 + h * 64;
#pragma unroll
  for (int rt = 0; rt < 2; ++rt)
#pragma unroll
    for (int ctd = 0; ctd < 4; ++ctd)
#pragma unroll
      for (int r = 0; r < 4; ++r) {
        int i = i0 + rt * 16 + quad * 4 + r;
        int d = ctd * 16 + l15;
        obase[(size_t)i * 1024 + d] = f2bf(oacc[rt][ctd][r] * linv[rt][r]);
      }
}

// ---------------------------------------------------------------------------
extern "C" void kernel_launch(void* const* d_in, const int* in_sizes, int n_in,
                              void* d_out, int out_size, void* d_ws, size_t ws_size,
                              hipStream_t stream) {
  const float* x = (const float*)d_in[0];
  const float* wqkv = (const float*)d_in[1];
  const float* wout = (const float*)d_in[2];
  float* out = (float*)d_out;
  char* ws = (char*)d_ws;

  short* qb = (short*)(ws + 0);            // [4,16,4096,64] bf16  (32 MiB)
  short* kb = (short*)(ws + 33554432);     // same
  short* vb = (short*)(ws + 67108864);     // same
  short* xb = (short*)(ws + 100663296);    // x bf16 [16384,1024]; reused as attn_out
  short* ab = xb;                          // alias: xb dead after GEMM1
  short* wqkvT = (short*)(ws + 134217728); // [3072,1024] bf16
  short* woutT = (short*)(ws + 140509184); // [1024,1024] bf16

  convert_x<<<8192, 256, 0, stream>>>(x, xb);
  transpose_w<<<dim3(16, 64), 256, 0, stream>>>(wqkv, wout, wqkvT, woutT);
  gemm256<0, 12><<<768, 512, 0, stream>>>(xb, wqkvT, nullptr, qb, kb, vb);
  attn_kernel<<<2048, 256, 0, stream>>>(qb, kb, vb, ab);
  gemm256<1, 4><<<256, 512, 0, stream>>>(ab, woutT, out, nullptr, nullptr, nullptr);
}

// Round 3
// 357.401 us; speedup vs baseline: 1.1395x; 1.0114x over previous
//
#include <hip/hip_runtime.h>
#include <stdint.h>

// LocalMHA on MI355X (gfx950).
// Pipeline: convert_x (f32->bf16) + transpose_w (LDS-tiled) ->
//           GEMM1 (qkv proj, 256x256 8-phase MFMA bf16, fused RoPE epilogue) ->
//           windowed attention (MFMA bf16, sliding window 129, no-max softmax) ->
//           GEMM2 (out proj, same 8-phase GEMM, fp32 store)
// GEMMs: 256^2 8-phase schedule, BK=64 double-buffered LDS ([16x32] bf16
// subtiles -> ds_read is base+lane*16, conflict-free; staging SOURCE is
// lane-permuted so the linear global_load_lds dest yields that layout),
// counted s_waitcnt vmcnt(6) (never 0 in main loop), setprio(1) around MFMA.
// SINGLE barrier per phase (round-3 change): the closing barrier is provably
// redundant — every plane's vmcnt-confirmation lands >=1 barrier before its
// first ds_read, and every DMA overwrite issues >=2 barriers after the last
// reader's lgkmcnt(0). One barrier/phase lets the 2 waves/SIMD skew by one
// phase so ds_reads/stage/vm-wait hide under the other wave's MFMA cluster.

typedef __attribute__((ext_vector_type(8))) short bfrag;  // 8 bf16 in 4 VGPRs
typedef __attribute__((ext_vector_type(4))) float f4;

#define MFMA_BF16(a, b, c) __builtin_amdgcn_mfma_f32_16x16x32_bf16((a), (b), (c), 0, 0, 0)

static __device__ __forceinline__ short f2bf(float f) {  // round-to-nearest-even
  unsigned u = __builtin_bit_cast(unsigned, f);
  u = (u + 0x7fffu + ((u >> 16) & 1u)) >> 16;
  return (short)u;
}
static __device__ __forceinline__ float bf2f(short s) {
  unsigned u = ((unsigned)(unsigned short)s) << 16;
  return __builtin_bit_cast(float, u);
}

typedef __attribute__((address_space(3))) unsigned lds_u;
typedef __attribute__((address_space(1))) unsigned gbl_u;

// global -> LDS direct DMA, 16B/lane. LDS dest = wave-uniform base + lane*16.
static __device__ __forceinline__ void gl_lds16(const void* g, const void* lds) {
  unsigned loff = (unsigned)__builtin_amdgcn_readfirstlane((int)(uintptr_t)lds);
  __builtin_amdgcn_global_load_lds((gbl_u*)(uintptr_t)g, (lds_u*)(uintptr_t)loff, 16, 0, 0);
}

// ---------------------------------------------------------------------------
// Kernel 1a: x (16384x1024 f32) -> xb bf16, vectorized 8 elems/thread.
// ---------------------------------------------------------------------------
__global__ __launch_bounds__(256) void convert_x(const float* __restrict__ x,
                                                 short* __restrict__ xb) {
  int idx = blockIdx.x * 256 + threadIdx.x;  // 2M threads x 8 elems
  size_t base = (size_t)idx * 8;
  float4 a = *(const float4*)(x + base);
  float4 b = *(const float4*)(x + base + 4);
  bfrag o;
  o[0] = f2bf(a.x); o[1] = f2bf(a.y); o[2] = f2bf(a.z); o[3] = f2bf(a.w);
  o[4] = f2bf(b.x); o[5] = f2bf(b.y); o[6] = f2bf(b.z); o[7] = f2bf(b.w);
  *(bfrag*)(xb + base) = o;
}

// ---------------------------------------------------------------------------
// Kernel 1b: LDS-tiled 64x64 transpose+convert of W_qkv [1024,3072] and
// W_out [1024,1024] into N-major bf16 (coalesced reads AND writes).
// grid (16, 64): y<48 -> wqkv tile, else wout tile (y-48).
// ---------------------------------------------------------------------------
__global__ __launch_bounds__(256) void transpose_w(
    const float* __restrict__ wqkv, const float* __restrict__ wout,
    short* __restrict__ wqkvT, short* __restrict__ woutT) {
  __shared__ short t[64][72];
  const int tid = threadIdx.x;
  const int kt = blockIdx.x, yt = blockIdx.y;
  const float* src; short* dst; int N, nt;
  if (yt < 48) { src = wqkv; dst = wqkvT; N = 3072; nt = yt; }
  else         { src = wout; dst = woutT; N = 1024; nt = yt - 48; }
  const int k0 = kt * 64, n0 = nt * 64;
#pragma unroll
  for (int i = 0; i < 4; ++i) {
    int r = i * 16 + (tid >> 4);  // k-local
    int c = (tid & 15) * 4;       // n-local
    float4 v = *(const float4*)(src + (size_t)(k0 + r) * N + n0 + c);
    t[c + 0][r] = f2bf(v.x);
    t[c + 1][r] = f2bf(v.y);
    t[c + 2][r] = f2bf(v.z);
    t[c + 3][r] = f2bf(v.w);
  }
  __syncthreads();
#pragma unroll
  for (int i = 0; i < 2; ++i) {
    int c = tid + i * 256;
    int n = c >> 3, k8 = (c & 7) * 8;
    *(bfrag*)(dst + (size_t)(n0 + n) * 1024 + k0 + k8) = *(const bfrag*)&t[n][k8];
  }
}

// ---------------------------------------------------------------------------
// 256x256 8-phase bf16 GEMM: C[M,N] = A[M,1024] * Bt[N,1024]^T.
// 512 threads = 8 waves (2 M-waves x 4 N-waves); each wave owns 128x64.
// BK=64 as two 32-wide k-planes; LDS 128 KiB (2 dbuf x 2 planes x A,B).
// Plane layout: 16 subtiles of [16 rows][32 k] bf16 (1024 B contiguous).
// Granule g of a subtile holds logical (row=g&15, kgrp=g>>4) -> MFMA frag read
// is base+lane*16 (linear, conflict-free); staging SOURCE is lane-permuted.
// Phase = {8 ds_read; stage 1 plane; counted vmcnt; s_barrier; lgkmcnt(0);
// 16 MFMA in setprio(1)}. ONE barrier per phase (see header comment).
// MODE 0: RoPE+scale epilogue scatters into q/k/v [B,H,N,64] bf16.
// MODE 1: plain fp32 C store (output projection).
// ---------------------------------------------------------------------------
#define VM6 asm volatile("s_waitcnt vmcnt(6)" ::: "memory")
#define VM4 asm volatile("s_waitcnt vmcnt(4)" ::: "memory")
#define VM0 asm volatile("s_waitcnt vmcnt(0)" ::: "memory")
#define VNOP ((void)0)

// stage one 16 KiB k-plane (2 x global_load_lds per thread)
#define ST_A(buf, ks, kk)                                                          \
  do {                                                                             \
    gl_lds16(aS0 + (ks) * 32 + (kk), ldsA + (buf) * 32768 + (ks) * 16384 + stA);   \
    gl_lds16(aS1 + (ks) * 32 + (kk),                                               \
             ldsA + (buf) * 32768 + (ks) * 16384 + 8192 + stA);                    \
  } while (0)
#define ST_B(buf, ks, kk)                                                          \
  do {                                                                             \
    gl_lds16(bS0 + (ks) * 32 + (kk), ldsB + (buf) * 32768 + (ks) * 16384 + stA);   \
    gl_lds16(bS1 + (ks) * 32 + (kk),                                               \
             ldsB + (buf) * 32768 + (ks) * 16384 + 8192 + stA);                    \
  } while (0)

#define MM4(mi, a)                                 \
  acc[mi][0] = MFMA_BF16(a, b0, acc[mi][0]);       \
  acc[mi][1] = MFMA_BF16(a, b1, acc[mi][1]);       \
  acc[mi][2] = MFMA_BF16(a, b2, acc[mi][2]);       \
  acc[mi][3] = MFMA_BF16(a, b3, acc[mi][3])

#define PHASE(buf, ks, mh, STAGE, WAIT)                                            \
  {                                                                                \
    const char* pA_ = ldsA + (buf) * 32768 + (ks) * 16384 + (mh) * 4096 + aRd;     \
    const char* pB_ = ldsB + (buf) * 32768 + (ks) * 16384 + bRd;                   \
    bfrag a0 = *(const bfrag*)(pA_);                                               \
    bfrag a1 = *(const bfrag*)(pA_ + 1024);                                        \
    bfrag a2 = *(const bfrag*)(pA_ + 2048);                                        \
    bfrag a3 = *(const bfrag*)(pA_ + 3072);                                        \
    bfrag b0 = *(const bfrag*)(pB_);                                               \
    bfrag b1 = *(const bfrag*)(pB_ + 1024);                                        \
    bfrag b2 = *(const bfrag*)(pB_ + 2048);                                        \
    bfrag b3 = *(const bfrag*)(pB_ + 3072);                                        \
    STAGE;                                                                         \
    WAIT;                                                                          \
    __builtin_amdgcn_s_barrier();                                                  \
    asm volatile("s_waitcnt lgkmcnt(0)" ::: "memory");                             \
    __builtin_amdgcn_sched_barrier(0);                                             \
    __builtin_amdgcn_s_setprio(1);                                                 \
    MM4((mh) * 4 + 0, a0);                                                         \
    MM4((mh) * 4 + 1, a1);                                                         \
    MM4((mh) * 4 + 2, a2);                                                         \
    MM4((mh) * 4 + 3, a3);                                                         \
    __builtin_amdgcn_s_setprio(0);                                                 \
  }

template <int MODE, int NBX>
__global__ __launch_bounds__(512, 2) void gemm256(
    const short* __restrict__ A, const short* __restrict__ Bt, float* __restrict__ C,
    short* __restrict__ oq, short* __restrict__ ok, short* __restrict__ ov) {
  __shared__ __align__(1024) char lds[131072];  // A: [0,64K) B: [64K,128K)
  char* const ldsA = lds;
  char* const ldsB = lds + 65536;

  const int tid = threadIdx.x, lane = tid & 63, wv = tid >> 6;
  const int wr = wv >> 2, wc = wv & 3;
  const int l15 = lane & 15, quad = lane >> 4;

  // XCD-aware bijective swizzle (nwg = NBX*64, divisible by 8).
  const int nwg = NBX * 64;
  const int bid = (int)blockIdx.x;
  const int wgid = (bid & 7) * (nwg >> 3) + (bid >> 3);
  const int bx = wgid % NBX, by = wgid / NBX;

  const short* Ab = A + (size_t)by * 256 * 1024;
  const short* Bb = Bt + (size_t)bx * 256 * 1024;

  // Staging source: DMA lane l writes LDS granule l of the wave's subtile;
  // granule l must hold logical (row = l&15, kgrp = l>>4).
  const int srow = lane & 15, scg = lane >> 4;
  const short* aS0 = Ab + (size_t)(wv * 16 + srow) * 1024 + scg * 8;
  const short* aS1 = Ab + (size_t)((8 + wv) * 16 + srow) * 1024 + scg * 8;
  const short* bS0 = Bb + (size_t)(wv * 16 + srow) * 1024 + scg * 8;
  const short* bS1 = Bb + (size_t)((8 + wv) * 16 + srow) * 1024 + scg * 8;
  const int stA = wv * 1024;  // wave-uniform LDS dest offset (call0; call1 +8192)

  // ds_read: linear base + lane*16 within each subtile.
  const int rdoff = lane * 16;
  const int aRd = wr * 8192 + rdoff;  // + mh*4096 + m*1024
  const int bRd = wc * 4096 + rdoff;  // + n*1024

  f4 acc[8][4];
#pragma unroll
  for (int i = 0; i < 8; ++i)
#pragma unroll
    for (int j = 0; j < 4; ++j) acc[i][j] = (f4)0.f;

  // ---- prologue: tile0 all 4 planes + tile1 A-ks0; wait oldest 2 planes ----
  ST_A(0, 0, 0); ST_B(0, 0, 0); ST_A(0, 1, 0); ST_B(0, 1, 0); ST_A(1, 0, 64);
  VM6;
  __builtin_amdgcn_s_barrier();

  // ---- main loop: tile pairs (t,buf0),(t+1,buf1), t = 0..12 ----
#pragma unroll 1
  for (int t = 0; t < 14; t += 2) {
    const int kk1 = t * 64 + 64, kk2 = t * 64 + 128, kk3 = t * 64 + 192;
    PHASE(0, 0, 0, ST_B(1, 0, kk1), VNOP);  // stage (t+1,B0)
    PHASE(0, 0, 1, ST_A(1, 1, kk1), VM6);   // stage (t+1,A1); covers (t,A1/B1)
    PHASE(0, 1, 0, ST_B(1, 1, kk1), VNOP);  // stage (t+1,B1)
    PHASE(0, 1, 1, ST_A(0, 0, kk2), VM6);   // stage (t+2,A0); covers (t+1,A0/B0)
    PHASE(1, 0, 0, ST_B(0, 0, kk2), VNOP);
    PHASE(1, 0, 1, ST_A(0, 1, kk2), VM6);
    PHASE(1, 1, 0, ST_B(0, 1, kk2), VNOP);
    PHASE(1, 1, 1, ST_A(1, 0, kk3), VM6);
  }

  // ---- drain: tile 14 (buf0) stages tile 15 remainder; tile 15 (buf1) ----
  PHASE(0, 0, 0, ST_B(1, 0, 960), VNOP);
  PHASE(0, 0, 1, ST_A(1, 1, 960), VM6);
  PHASE(0, 1, 0, ST_B(1, 1, 960), VNOP);
  PHASE(0, 1, 1, VNOP, VM4);  // covers (15,A0/B0); leaves (15,A1/B1) in flight
  PHASE(1, 0, 0, VNOP, VNOP);
  PHASE(1, 0, 1, VNOP, VM0);  // final drain for (15,A1/B1)
  PHASE(1, 1, 0, VNOP, VNOP);
  PHASE(1, 1, 1, VNOP, VNOP);

  // ---- epilogue: C/D layout col=lane&15, row=quad*4+reg ----
  if constexpr (MODE == 0) {
    const int n64 = bx * 256 + wc * 64;  // 64-aligned -> one (part, head)
    const int part = n64 >> 10;          // 0=q 1=k 2=v (wave-uniform)
    const int head = (n64 & 1023) >> 6;
    short* o = (part == 0) ? oq : (part == 1) ? ok : ov;
    const float f0 = exp2f((float)l15 * -0.41524101186f);  // 10000^(-d/32)
    const float f1 = exp2f((float)(16 + l15) * -0.41524101186f);
#pragma unroll
    for (int i = 0; i < 8; ++i)
#pragma unroll
      for (int r = 0; r < 4; ++r) {
        const int m = by * 256 + wr * 128 + i * 16 + quad * 4 + r;
        const int b = m >> 12, p = m & 4095;
        short* row = o + ((size_t)(b * 16 + head) * 4096 + p) * 64;
        if (part == 2) {
#pragma unroll
          for (int j = 0; j < 4; ++j) row[j * 16 + l15] = f2bf(acc[i][j][r]);
        } else {
#pragma unroll
          for (int j = 0; j < 2; ++j) {
            float av = acc[i][j][r], bv2 = acc[i][j + 2][r];
            float sn, cs;
            __sincosf((float)p * (j ? f1 : f0), &sn, &cs);
            float ra = av * cs - bv2 * sn;
            float rb = bv2 * cs + av * sn;
            if (part == 0) { ra *= 0.125f; rb *= 0.125f; }
            row[j * 16 + l15] = f2bf(ra);
            row[32 + j * 16 + l15] = f2bf(rb);
          }
        }
      }
  } else {
#pragma unroll
    for (int i = 0; i < 8; ++i)
#pragma unroll
      for (int j = 0; j < 4; ++j)
#pragma unroll
        for (int r = 0; r < 4; ++r) {
          int m = by * 256 + wr * 128 + i * 16 + quad * 4 + r;
          int n = bx * 256 + wc * 64 + j * 16 + l15;
          C[(size_t)m * 1024 + n] = acc[i][j][r];
        }
  }
}

// ---------------------------------------------------------------------------
// Kernel 3: windowed attention. One block (256 thr, 4 waves) per (b,h,w).
// Keys for window w: abs positions [w*128-128, w*128+128). Valid keys for
// query i (window-local): jj in [i, i+128], plus jj>=128 when w==0.
// Softmax without max-subtraction: q pre-scaled by 0.125 -> |sim| << 88.
// ---------------------------------------------------------------------------
__global__ __launch_bounds__(256) void attn_kernel(
    const short* __restrict__ qb, const short* __restrict__ kb,
    const short* __restrict__ vb, short* __restrict__ ob) {
  constexpr int KST = 72, VST = 264, PST = 136;
  __shared__ __align__(16) short smem[18432 + 16896];  // 69 KB -> 2 blocks/CU
  short* Ks = smem;          // 256 x KST; aliased by P (128 x PST)
  short* Pl = smem;
  short* Vt = smem + 18432;  // 64 x VST (V transposed)

  const int bid = blockIdx.x;
  const int w = bid & 31, bh = bid >> 5;
  const int tid = threadIdx.x, lane = tid & 63, wv = tid >> 6;
  const int l15 = lane & 15, quad = lane >> 4;
  const size_t kvbase = (size_t)bh * (4096 * 64);
  const int pk0 = w * 128 - 128;

  // ---- Q A-frags straight from global (issued early to overlap staging) ----
  const int i0 = wv * 32;  // this wave's 32 query rows
  const short* qbase = qb + kvbase + (size_t)(w * 128) * 64;
  bfrag aq[2][2];
#pragma unroll
  for (int rt = 0; rt < 2; ++rt)
#pragma unroll
    for (int ks = 0; ks < 2; ++ks)
      aq[rt][ks] = *(const bfrag*)(qbase + (size_t)(i0 + rt * 16 + l15) * 64 + ks * 32 + quad * 8);

  // ---- stage K (row layout) and V^T ----
#pragma unroll
  for (int i = 0; i < 8; ++i) {
    int c = tid + i * 256;  // 2048 x 16B chunks
    int row = c >> 3;       // key index jj 0..255
    int d0 = (c & 7) * 8;
    int pk = pk0 + row;
    if (pk < 0) pk = 0;  // OOB keys are masked; clamp to stay in bounds
    const size_t src = kvbase + (size_t)pk * 64 + d0;
    bfrag kvv = *(const bfrag*)(kb + src);
    *(bfrag*)&Ks[row * KST + d0] = kvv;
    bfrag vvv = *(const bfrag*)(vb + src);
#pragma unroll
    for (int j = 0; j < 8; ++j) Vt[(d0 + j) * VST + row] = vvv[j];
  }
  __syncthreads();

  // ---- sim = Q K^T : 2 row-tiles x 16 col-tiles ----
  f4 sim[2][16];
#pragma unroll
  for (int rt = 0; rt < 2; ++rt)
#pragma unroll
    for (int ct = 0; ct < 16; ++ct) sim[rt][ct] = (f4)0.f;

#pragma unroll
  for (int ct = 0; ct < 16; ++ct) {
    bfrag bk0 = *(const bfrag*)&Ks[(ct * 16 + l15) * KST + quad * 8];
    bfrag bk1 = *(const bfrag*)&Ks[(ct * 16 + l15) * KST + 32 + quad * 8];
#pragma unroll
    for (int rt = 0; rt < 2; ++rt) {
      sim[rt][ct] = MFMA_BF16(aq[rt][0], bk0, sim[rt][ct]);
      sim[rt][ct] = MFMA_BF16(aq[rt][1], bk1, sim[rt][ct]);
    }
  }
  __syncthreads();  // all K reads done; Ks region free for P

  // ---- masked softmax, no max-subtraction (values bounded; fp32 exp safe) ----
  float linv[2][4];
#pragma unroll
  for (int rt = 0; rt < 2; ++rt)
#pragma unroll
    for (int r = 0; r < 4; ++r) {
      const int iloc = i0 + rt * 16 + quad * 4 + r;
      float sum = 0.f;
#pragma unroll
      for (int ct = 0; ct < 16; ++ct) {
        int jj = ct * 16 + l15;
        bool valid = (jj >= iloc) && (jj <= iloc + 128) && ((w > 0) || (jj >= 128));
        float pv = valid ? __expf(sim[rt][ct][r]) : 0.f;
        sim[rt][ct][r] = pv;
        sum += pv;
      }
#pragma unroll
      for (int off = 1; off < 16; off <<= 1) sum += __shfl_xor(sum, off);
      linv[rt][r] = 1.f / sum;
    }

  // ---- out = P V in two 128-key passes; P rows are wave-private in LDS ----
  f4 oacc[2][4];
#pragma unroll
  for (int rt = 0; rt < 2; ++rt)
#pragma unroll
    for (int ctd = 0; ctd < 4; ++ctd) oacc[rt][ctd] = (f4)0.f;

#pragma unroll
  for (int pass = 0; pass < 2; ++pass) {
#pragma unroll
    for (int rt = 0; rt < 2; ++rt)
#pragma unroll
      for (int ct = 0; ct < 8; ++ct) {
        int ctg = pass * 8 + ct;
#pragma unroll
        for (int r = 0; r < 4; ++r)
          Pl[(i0 + rt * 16 + quad * 4 + r) * PST + ct * 16 + l15] = f2bf(sim[rt][ctg][r]);
      }
    // same-wave DS ordering gives write->read visibility; rows disjoint per wave
#pragma unroll
    for (int ks = 0; ks < 4; ++ks) {
      bfrag ap[2];
#pragma unroll
      for (int rt = 0; rt < 2; ++rt)
        ap[rt] = *(const bfrag*)&Pl[(i0 + rt * 16 + l15) * PST + ks * 32 + quad * 8];
#pragma unroll
      for (int ctd = 0; ctd < 4; ++ctd) {
        bfrag bv = *(const bfrag*)&Vt[(ctd * 16 + l15) * VST + pass * 128 + ks * 32 + quad * 8];
#pragma unroll
        for (int rt = 0; rt < 2; ++rt) oacc[rt][ctd] = MFMA_BF16(ap[rt], bv, oacc[rt][ctd]);
      }
    }
  }

  // ---- epilogue: normalize and write [b][p][h*64+d] bf16 ----
  const int b = bh >> 4, h = bh & 15;
  short* obase = ob + ((size_t)b * 4096 + w * 128) * 1024 + h * 64;
#pragma unroll
  for (int rt = 0; rt < 2; ++rt)
#pragma unroll
    for (int ctd = 0; ctd < 4; ++ctd)
#pragma unroll
      for (int r = 0; r < 4; ++r) {
        int i = i0 + rt * 16 + quad * 4 + r;
        int d = ctd * 16 + l15;
        obase[(size_t)i * 1024 + d] = f2bf(oacc[rt][ctd][r] * linv[rt][r]);
      }
}

// ---------------------------------------------------------------------------
extern "C" void kernel_launch(void* const* d_in, const int* in_sizes, int n_in,
                              void* d_out, int out_size, void* d_ws, size_t ws_size,
                              hipStream_t stream) {
  const float* x = (const float*)d_in[0];
  const float* wqkv = (const float*)d_in[1];
  const float* wout = (const float*)d_in[2];
  float* out = (float*)d_out;
  char* ws = (char*)d_ws;

  short* qb = (short*)(ws + 0);            // [4,16,4096,64] bf16  (32 MiB)
  short* kb = (short*)(ws + 33554432);     // same
  short* vb = (short*)(ws + 67108864);     // same
  short* xb = (short*)(ws + 100663296);    // x bf16 [16384,1024]; reused as attn_out
  short* ab = xb;                          // alias: xb dead after GEMM1
  short* wqkvT = (short*)(ws + 134217728); // [3072,1024] bf16
  short* woutT = (short*)(ws + 140509184); // [1024,1024] bf16

  convert_x<<<8192, 256, 0, stream>>>(x, xb);
  transpose_w<<<dim3(16, 64), 256, 0, stream>>>(wqkv, wout, wqkvT, woutT);
  gemm256<0, 12><<<768, 512, 0, stream>>>(xb, wqkvT, nullptr, qb, kb, vb);
  attn_kernel<<<2048, 256, 0, stream>>>(qb, kb, vb, ab);
  gemm256<1, 4><<<256, 512, 0, stream>>>(ab, woutT, out, nullptr, nullptr, nullptr);
}

// Round 4
// 356.039 us; speedup vs baseline: 1.1438x; 1.0038x over previous
//
#include <hip/hip_runtime.h>
#include <stdint.h>

// LocalMHA on MI355X (gfx950).
// Pipeline: convert_x (f32->bf16) + transpose_w (LDS-tiled) ->
//           GEMM1 (qkv proj, 256x256 MFMA bf16, fused RoPE epilogue) ->
//           windowed attention (MFMA bf16, sliding window 129, no-max softmax) ->
//           GEMM2 (out proj, same GEMM, fp32 store)
// GEMM round-4 structure: BK=64 as two 32-k planes, double-buffered LDS
// ([16x32] bf16 subtiles -> ds_read is base+lane*16, conflict-free; staging
// SOURCE is lane-permuted so the linear global_load_lds dest yields that
// layout). ONE barrier-interval per PLANE (32 phases/block): each phase does
// 12 ds_read_b128 + stage-next-next-plane (4 gl_lds16) + counted vmcnt(4) +
// s_barrier + lgkmcnt(0) + 32 MFMA in setprio(1). Rationale: measured
// overhead per barrier-interval is ~fixed (~1100 cy), so halving intervals
// while doubling the MFMA cluster raises MfmaUtil. Hazard ledger: plane p+2's
// DMA overwrites plane p-2's slot; readers of p-2 are lgkm-confirmed by
// barrier(p-1), DMA issues after barrier(p-1) -> one full barrier separation.
// RoPE epilogue uses incremental complex rotation (6 sincos/thread instead of
// 64; <=32 rotation steps, drift << bf16 ulp).

typedef __attribute__((ext_vector_type(8))) short bfrag;  // 8 bf16 in 4 VGPRs
typedef __attribute__((ext_vector_type(4))) float f4;

#define MFMA_BF16(a, b, c) __builtin_amdgcn_mfma_f32_16x16x32_bf16((a), (b), (c), 0, 0, 0)

static __device__ __forceinline__ short f2bf(float f) {  // round-to-nearest-even
  unsigned u = __builtin_bit_cast(unsigned, f);
  u = (u + 0x7fffu + ((u >> 16) & 1u)) >> 16;
  return (short)u;
}
static __device__ __forceinline__ float bf2f(short s) {
  unsigned u = ((unsigned)(unsigned short)s) << 16;
  return __builtin_bit_cast(float, u);
}

typedef __attribute__((address_space(3))) unsigned lds_u;
typedef __attribute__((address_space(1))) unsigned gbl_u;

// global -> LDS direct DMA, 16B/lane. LDS dest = wave-uniform base + lane*16.
static __device__ __forceinline__ void gl_lds16(const void* g, const void* lds) {
  unsigned loff = (unsigned)__builtin_amdgcn_readfirstlane((int)(uintptr_t)lds);
  __builtin_amdgcn_global_load_lds((gbl_u*)(uintptr_t)g, (lds_u*)(uintptr_t)loff, 16, 0, 0);
}

// ---------------------------------------------------------------------------
// Kernel 1a: x (16384x1024 f32) -> xb bf16, vectorized 8 elems/thread.
// ---------------------------------------------------------------------------
__global__ __launch_bounds__(256) void convert_x(const float* __restrict__ x,
                                                 short* __restrict__ xb) {
  int idx = blockIdx.x * 256 + threadIdx.x;  // 2M threads x 8 elems
  size_t base = (size_t)idx * 8;
  float4 a = *(const float4*)(x + base);
  float4 b = *(const float4*)(x + base + 4);
  bfrag o;
  o[0] = f2bf(a.x); o[1] = f2bf(a.y); o[2] = f2bf(a.z); o[3] = f2bf(a.w);
  o[4] = f2bf(b.x); o[5] = f2bf(b.y); o[6] = f2bf(b.z); o[7] = f2bf(b.w);
  *(bfrag*)(xb + base) = o;
}

// ---------------------------------------------------------------------------
// Kernel 1b: LDS-tiled 64x64 transpose+convert of W_qkv [1024,3072] and
// W_out [1024,1024] into N-major bf16 (coalesced reads AND writes).
// grid (16, 64): y<48 -> wqkv tile, else wout tile (y-48).
// ---------------------------------------------------------------------------
__global__ __launch_bounds__(256) void transpose_w(
    const float* __restrict__ wqkv, const float* __restrict__ wout,
    short* __restrict__ wqkvT, short* __restrict__ woutT) {
  __shared__ short t[64][72];
  const int tid = threadIdx.x;
  const int kt = blockIdx.x, yt = blockIdx.y;
  const float* src; short* dst; int N, nt;
  if (yt < 48) { src = wqkv; dst = wqkvT; N = 3072; nt = yt; }
  else         { src = wout; dst = woutT; N = 1024; nt = yt - 48; }
  const int k0 = kt * 64, n0 = nt * 64;
#pragma unroll
  for (int i = 0; i < 4; ++i) {
    int r = i * 16 + (tid >> 4);  // k-local
    int c = (tid & 15) * 4;       // n-local
    float4 v = *(const float4*)(src + (size_t)(k0 + r) * N + n0 + c);
    t[c + 0][r] = f2bf(v.x);
    t[c + 1][r] = f2bf(v.y);
    t[c + 2][r] = f2bf(v.z);
    t[c + 3][r] = f2bf(v.w);
  }
  __syncthreads();
#pragma unroll
  for (int i = 0; i < 2; ++i) {
    int c = tid + i * 256;
    int n = c >> 3, k8 = (c & 7) * 8;
    *(bfrag*)(dst + (size_t)(n0 + n) * 1024 + k0 + k8) = *(const bfrag*)&t[n][k8];
  }
}

// ---------------------------------------------------------------------------
// 256x256 bf16 GEMM: C[M,N] = A[M,1024] * Bt[N,1024]^T.
// 512 threads = 8 waves (2 M-waves x 4 N-waves); each wave owns 128x64.
// LDS 128 KiB: 2 dbuf x 2 planes x (A 16 KiB + B 16 KiB). Plane = 16 subtiles
// of [16 rows][32 k] bf16. Granule g of a subtile holds (row=g&15, kgrp=g>>4)
// -> MFMA frag read is base+lane*16; staging SOURCE lane-permuted.
// 32 plane-phases; phase p stages plane p+2; vmcnt(4) each phase.
// MODE 0: RoPE+scale epilogue scatters into q/k/v [B,H,N,64] bf16.
// MODE 1: plain fp32 C store (output projection).
// ---------------------------------------------------------------------------
#define VM4 asm volatile("s_waitcnt vmcnt(4)" ::: "memory")
#define VM0 asm volatile("s_waitcnt vmcnt(0)" ::: "memory")
#define VNOP ((void)0)

// stage one 16 KiB k-plane of A or B (2 x global_load_lds per thread)
#define ST_A(buf, ks, kk)                                                          \
  do {                                                                             \
    gl_lds16(aS0 + (ks) * 32 + (kk), ldsA + (buf) * 32768 + (ks) * 16384 + stA);   \
    gl_lds16(aS1 + (ks) * 32 + (kk),                                               \
             ldsA + (buf) * 32768 + (ks) * 16384 + 8192 + stA);                    \
  } while (0)
#define ST_B(buf, ks, kk)                                                          \
  do {                                                                             \
    gl_lds16(bS0 + (ks) * 32 + (kk), ldsB + (buf) * 32768 + (ks) * 16384 + stA);   \
    gl_lds16(bS1 + (ks) * 32 + (kk),                                               \
             ldsB + (buf) * 32768 + (ks) * 16384 + 8192 + stA);                    \
  } while (0)
// stage one full plane-pair (A+B) = 4 loads/thread
#define ST2(buf, ks, kk) do { ST_A(buf, ks, kk); ST_B(buf, ks, kk); } while (0)

#define MM4(mi, a)                                 \
  acc[mi][0] = MFMA_BF16(a, b0, acc[mi][0]);       \
  acc[mi][1] = MFMA_BF16(a, b1, acc[mi][1]);       \
  acc[mi][2] = MFMA_BF16(a, b2, acc[mi][2]);       \
  acc[mi][3] = MFMA_BF16(a, b3, acc[mi][3])

// One barrier-interval: reads plane (buf,ks), 32 MFMA.
#define PHASE2(buf, ks, STAGE, WAIT)                                               \
  {                                                                                \
    const char* pA_ = ldsA + (buf) * 32768 + (ks) * 16384 + aRd;                   \
    const char* pB_ = ldsB + (buf) * 32768 + (ks) * 16384 + bRd;                   \
    bfrag a0 = *(const bfrag*)(pA_);                                               \
    bfrag a1 = *(const bfrag*)(pA_ + 1024);                                        \
    bfrag a2 = *(const bfrag*)(pA_ + 2048);                                        \
    bfrag a3 = *(const bfrag*)(pA_ + 3072);                                        \
    bfrag a4 = *(const bfrag*)(pA_ + 4096);                                        \
    bfrag a5 = *(const bfrag*)(pA_ + 5120);                                        \
    bfrag a6 = *(const bfrag*)(pA_ + 6144);                                        \
    bfrag a7 = *(const bfrag*)(pA_ + 7168);                                        \
    bfrag b0 = *(const bfrag*)(pB_);                                               \
    bfrag b1 = *(const bfrag*)(pB_ + 1024);                                        \
    bfrag b2 = *(const bfrag*)(pB_ + 2048);                                        \
    bfrag b3 = *(const bfrag*)(pB_ + 3072);                                        \
    STAGE;                                                                         \
    WAIT;                                                                          \
    __builtin_amdgcn_s_barrier();                                                  \
    asm volatile("s_waitcnt lgkmcnt(0)" ::: "memory");                             \
    __builtin_amdgcn_sched_barrier(0);                                             \
    __builtin_amdgcn_s_setprio(1);                                                 \
    MM4(0, a0);                                                                    \
    MM4(1, a1);                                                                    \
    MM4(2, a2);                                                                    \
    MM4(3, a3);                                                                    \
    MM4(4, a4);                                                                    \
    MM4(5, a5);                                                                    \
    MM4(6, a6);                                                                    \
    MM4(7, a7);                                                                    \
    __builtin_amdgcn_s_setprio(0);                                                 \
  }

template <int MODE, int NBX>
__global__ __launch_bounds__(512, 2) void gemm256(
    const short* __restrict__ A, const short* __restrict__ Bt, float* __restrict__ C,
    short* __restrict__ oq, short* __restrict__ ok, short* __restrict__ ov) {
  __shared__ __align__(1024) char lds[131072];  // A: [0,64K) B: [64K,128K)
  char* const ldsA = lds;
  char* const ldsB = lds + 65536;

  const int tid = threadIdx.x, lane = tid & 63, wv = tid >> 6;
  const int wr = wv >> 2, wc = wv & 3;
  const int l15 = lane & 15, quad = lane >> 4;

  // XCD-aware bijective swizzle (nwg = NBX*64, divisible by 8).
  const int nwg = NBX * 64;
  const int bid = (int)blockIdx.x;
  const int wgid = (bid & 7) * (nwg >> 3) + (bid >> 3);
  const int bx = wgid % NBX, by = wgid / NBX;

  const short* Ab = A + (size_t)by * 256 * 1024;
  const short* Bb = Bt + (size_t)bx * 256 * 1024;

  // Staging source: DMA lane l writes LDS granule l of the wave's subtile;
  // granule l must hold logical (row = l&15, kgrp = l>>4).
  const int srow = lane & 15, scg = lane >> 4;
  const short* aS0 = Ab + (size_t)(wv * 16 + srow) * 1024 + scg * 8;
  const short* aS1 = Ab + (size_t)((8 + wv) * 16 + srow) * 1024 + scg * 8;
  const short* bS0 = Bb + (size_t)(wv * 16 + srow) * 1024 + scg * 8;
  const short* bS1 = Bb + (size_t)((8 + wv) * 16 + srow) * 1024 + scg * 8;
  const int stA = wv * 1024;  // wave-uniform LDS dest offset (call0; call1 +8192)

  // ds_read: linear base + lane*16 within each subtile.
  const int aRd = wr * 8192 + lane * 16;  // + sub*1024 (8 subtiles = 128 rows)
  const int bRd = wc * 4096 + lane * 16;  // + sub*1024 (4 subtiles = 64 rows)

  f4 acc[8][4];
#pragma unroll
  for (int i = 0; i < 8; ++i)
#pragma unroll
    for (int j = 0; j < 4; ++j) acc[i][j] = (f4)0.f;

  // ---- prologue: planes 0,1 (tile0); wait oldest plane ----
  ST2(0, 0, 0); ST2(0, 1, 0);
  VM4;
  __builtin_amdgcn_s_barrier();

  // ---- main loop: 4 plane-phases per tile pair, t = 0..13 ----
#pragma unroll 1
  for (int t = 0; t < 14; t += 2) {
    const int kn = t * 64 + 64, kn2 = t * 64 + 128;
    PHASE2(0, 0, ST2(1, 0, kn), VM4);   // read plane 2t,   stage plane 2t+2
    PHASE2(0, 1, ST2(1, 1, kn), VM4);   // read plane 2t+1, stage plane 2t+3
    PHASE2(1, 0, ST2(0, 0, kn2), VM4);  // read plane 2t+2, stage plane 2t+4
    PHASE2(1, 1, ST2(0, 1, kn2), VM4);  // read plane 2t+3, stage plane 2t+5
  }

  // ---- tail: tiles 14,15 ----
  PHASE2(0, 0, ST2(1, 0, 960), VM4);
  PHASE2(0, 1, ST2(1, 1, 960), VM4);
  PHASE2(1, 0, VNOP, VM0);  // drain: only plane 31 outstanding
  PHASE2(1, 1, VNOP, VNOP);

  // ---- epilogue: C/D layout col=lane&15, row=quad*4+reg ----
  if constexpr (MODE == 0) {
    const int n64 = bx * 256 + wc * 64;  // 64-aligned -> one (part, head)
    const int part = n64 >> 10;          // 0=q 1=k 2=v (wave-uniform)
    const int head = (n64 & 1023) >> 6;
    short* o = (part == 0) ? oq : (part == 1) ? ok : ov;
    const int mbase = by * 256 + wr * 128;  // block half spans 128 rows, one batch
    const int bb = mbase >> 12;
    const int p0 = (mbase & 4095) + quad * 4;  // position at (i=0, r=0)
    short* const obase = o + (size_t)(bb * 16 + head) * 4096 * 64;
    if (part == 2) {
#pragma unroll
      for (int i = 0; i < 8; ++i)
#pragma unroll
        for (int r = 0; r < 4; ++r) {
          short* row = obase + (size_t)(p0 + i * 16 + r) * 64;
#pragma unroll
          for (int j = 0; j < 4; ++j) row[j * 16 + l15] = f2bf(acc[i][j][r]);
        }
    } else {
      const float qs = (part == 0) ? 0.125f : 1.0f;
      // freq per lane: 10000^(-(j*16+l15)/32) = exp2(-(j*16+l15)*0.41524101)
      float fr[2], c1[2], s1[2], cD[2], sD[2], cs[2], sn[2];
      fr[0] = exp2f((float)l15 * -0.41524101186f);
      fr[1] = exp2f((float)(16 + l15) * -0.41524101186f);
#pragma unroll
      for (int j = 0; j < 2; ++j) {
        __sincosf(fr[j], &s1[j], &c1[j]);            // step +1 position
        __sincosf(13.0f * fr[j], &sD[j], &cD[j]);    // step +13 (r=3 -> next i)
        __sincosf((float)p0 * fr[j], &sn[j], &cs[j]);
      }
#pragma unroll
      for (int i = 0; i < 8; ++i) {
#pragma unroll
        for (int r = 0; r < 4; ++r) {
          short* row = obase + (size_t)(p0 + i * 16 + r) * 64;
#pragma unroll
          for (int j = 0; j < 2; ++j) {
            float av = acc[i][j][r], bv2 = acc[i][j + 2][r];
            float ra = (av * cs[j] - bv2 * sn[j]) * qs;
            float rb = (bv2 * cs[j] + av * sn[j]) * qs;
            row[j * 16 + l15] = f2bf(ra);
            row[32 + j * 16 + l15] = f2bf(rb);
          }
          if (r < 3) {
#pragma unroll
            for (int j = 0; j < 2; ++j) {
              float nc = cs[j] * c1[j] - sn[j] * s1[j];
              sn[j] = sn[j] * c1[j] + cs[j] * s1[j];
              cs[j] = nc;
            }
          }
        }
#pragma unroll
        for (int j = 0; j < 2; ++j) {
          float nc = cs[j] * cD[j] - sn[j] * sD[j];
          sn[j] = sn[j] * cD[j] + cs[j] * sD[j];
          cs[j] = nc;
        }
      }
    }
  } else {
#pragma unroll
    for (int i = 0; i < 8; ++i)
#pragma unroll
      for (int j = 0; j < 4; ++j)
#pragma unroll
        for (int r = 0; r < 4; ++r) {
          int m = by * 256 + wr * 128 + i * 16 + quad * 4 + r;
          int n = bx * 256 + wc * 64 + j * 16 + l15;
          C[(size_t)m * 1024 + n] = acc[i][j][r];
        }
  }
}

// ---------------------------------------------------------------------------
// Kernel 3: windowed attention. One block (256 thr, 4 waves) per (b,h,w).
// Keys for window w: abs positions [w*128-128, w*128+128). Valid keys for
// query i (window-local): jj in [i, i+128], plus jj>=128 when w==0.
// Softmax without max-subtraction: q pre-scaled by 0.125 -> |sim| << 88.
// ---------------------------------------------------------------------------
__global__ __launch_bounds__(256) void attn_kernel(
    const short* __restrict__ qb, const short* __restrict__ kb,
    const short* __restrict__ vb, short* __restrict__ ob) {
  constexpr int KST = 72, VST = 264, PST = 136;
  __shared__ __align__(16) short smem[18432 + 16896];  // 69 KB -> 2 blocks/CU
  short* Ks = smem;          // 256 x KST; aliased by P (128 x PST)
  short* Pl = smem;
  short* Vt = smem + 18432;  // 64 x VST (V transposed)

  const int bid = blockIdx.x;
  const int w = bid & 31, bh = bid >> 5;
  const int tid = threadIdx.x, lane = tid & 63, wv = tid >> 6;
  const int l15 = lane & 15, quad = lane >> 4;
  const size_t kvbase = (size_t)bh * (4096 * 64);
  const int pk0 = w * 128 - 128;

  // ---- Q A-frags straight from global (issued early to overlap staging) ----
  const int i0 = wv * 32;  // this wave's 32 query rows
  const short* qbase = qb + kvbase + (size_t)(w * 128) * 64;
  bfrag aq[2][2];
#pragma unroll
  for (int rt = 0; rt < 2; ++rt)
#pragma unroll
    for (int ks = 0; ks < 2; ++ks)
      aq[rt][ks] = *(const bfrag*)(qbase + (size_t)(i0 + rt * 16 + l15) * 64 + ks * 32 + quad * 8);

  // ---- stage K (row layout) and V^T ----
#pragma unroll
  for (int i = 0; i < 8; ++i) {
    int c = tid + i * 256;  // 2048 x 16B chunks
    int row = c >> 3;       // key index jj 0..255
    int d0 = (c & 7) * 8;
    int pk = pk0 + row;
    if (pk < 0) pk = 0;  // OOB keys are masked; clamp to stay in bounds
    const size_t src = kvbase + (size_t)pk * 64 + d0;
    bfrag kvv = *(const bfrag*)(kb + src);
    *(bfrag*)&Ks[row * KST + d0] = kvv;
    bfrag vvv = *(const bfrag*)(vb + src);
#pragma unroll
    for (int j = 0; j < 8; ++j) Vt[(d0 + j) * VST + row] = vvv[j];
  }
  __syncthreads();

  // ---- sim = Q K^T : 2 row-tiles x 16 col-tiles ----
  f4 sim[2][16];
#pragma unroll
  for (int rt = 0; rt < 2; ++rt)
#pragma unroll
    for (int ct = 0; ct < 16; ++ct) sim[rt][ct] = (f4)0.f;

#pragma unroll
  for (int ct = 0; ct < 16; ++ct) {
    bfrag bk0 = *(const bfrag*)&Ks[(ct * 16 + l15) * KST + quad * 8];
    bfrag bk1 = *(const bfrag*)&Ks[(ct * 16 + l15) * KST + 32 + quad * 8];
#pragma unroll
    for (int rt = 0; rt < 2; ++rt) {
      sim[rt][ct] = MFMA_BF16(aq[rt][0], bk0, sim[rt][ct]);
      sim[rt][ct] = MFMA_BF16(aq[rt][1], bk1, sim[rt][ct]);
    }
  }
  __syncthreads();  // all K reads done; Ks region free for P

  // ---- masked softmax, no max-subtraction (values bounded; fp32 exp safe) ----
  float linv[2][4];
#pragma unroll
  for (int rt = 0; rt < 2; ++rt)
#pragma unroll
    for (int r = 0; r < 4; ++r) {
      const int iloc = i0 + rt * 16 + quad * 4 + r;
      float sum = 0.f;
#pragma unroll
      for (int ct = 0; ct < 16; ++ct) {
        int jj = ct * 16 + l15;
        bool valid = (jj >= iloc) && (jj <= iloc + 128) && ((w > 0) || (jj >= 128));
        float pv = valid ? __expf(sim[rt][ct][r]) : 0.f;
        sim[rt][ct][r] = pv;
        sum += pv;
      }
#pragma unroll
      for (int off = 1; off < 16; off <<= 1) sum += __shfl_xor(sum, off);
      linv[rt][r] = 1.f / sum;
    }

  // ---- out = P V in two 128-key passes; P rows are wave-private in LDS ----
  f4 oacc[2][4];
#pragma unroll
  for (int rt = 0; rt < 2; ++rt)
#pragma unroll
    for (int ctd = 0; ctd < 4; ++ctd) oacc[rt][ctd] = (f4)0.f;

#pragma unroll
  for (int pass = 0; pass < 2; ++pass) {
#pragma unroll
    for (int rt = 0; rt < 2; ++rt)
#pragma unroll
      for (int ct = 0; ct < 8; ++ct) {
        int ctg = pass * 8 + ct;
#pragma unroll
        for (int r = 0; r < 4; ++r)
          Pl[(i0 + rt * 16 + quad * 4 + r) * PST + ct * 16 + l15] = f2bf(sim[rt][ctg][r]);
      }
    // same-wave DS ordering gives write->read visibility; rows disjoint per wave
#pragma unroll
    for (int ks = 0; ks < 4; ++ks) {
      bfrag ap[2];
#pragma unroll
      for (int rt = 0; rt < 2; ++rt)
        ap[rt] = *(const bfrag*)&Pl[(i0 + rt * 16 + l15) * PST + ks * 32 + quad * 8];
#pragma unroll
      for (int ctd = 0; ctd < 4; ++ctd) {
        bfrag bv = *(const bfrag*)&Vt[(ctd * 16 + l15) * VST + pass * 128 + ks * 32 + quad * 8];
#pragma unroll
        for (int rt = 0; rt < 2; ++rt) oacc[rt][ctd] = MFMA_BF16(ap[rt], bv, oacc[rt][ctd]);
      }
    }
  }

  // ---- epilogue: normalize and write [b][p][h*64+d] bf16 ----
  const int b = bh >> 4, h = bh & 15;
  short* obase = ob + ((size_t)b * 4096 + w * 128) * 1024 + h * 64;
#pragma unroll
  for (int rt = 0; rt < 2; ++rt)
#pragma unroll
    for (int ctd = 0; ctd < 4; ++ctd)
#pragma unroll
      for (int r = 0; r < 4; ++r) {
        int i = i0 + rt * 16 + quad * 4 + r;
        int d = ctd * 16 + l15;
        obase[(size_t)i * 1024 + d] = f2bf(oacc[rt][ctd][r] * linv[rt][r]);
      }
}

// ---------------------------------------------------------------------------
extern "C" void kernel_launch(void* const* d_in, const int* in_sizes, int n_in,
                              void* d_out, int out_size, void* d_ws, size_t ws_size,
                              hipStream_t stream) {
  const float* x = (const float*)d_in[0];
  const float* wqkv = (const float*)d_in[1];
  const float* wout = (const float*)d_in[2];
  float* out = (float*)d_out;
  char* ws = (char*)d_ws;

  short* qb = (short*)(ws + 0);            // [4,16,4096,64] bf16  (32 MiB)
  short* kb = (short*)(ws + 33554432);     // same
  short* vb = (short*)(ws + 67108864);     // same
  short* xb = (short*)(ws + 100663296);    // x bf16 [16384,1024]; reused as attn_out
  short* ab = xb;                          // alias: xb dead after GEMM1
  short* wqkvT = (short*)(ws + 134217728); // [3072,1024] bf16
  short* woutT = (short*)(ws + 140509184); // [1024,1024] bf16

  convert_x<<<8192, 256, 0, stream>>>(x, xb);
  transpose_w<<<dim3(16, 64), 256, 0, stream>>>(wqkv, wout, wqkvT, woutT);
  gemm256<0, 12><<<768, 512, 0, stream>>>(xb, wqkvT, nullptr, qb, kb, vb);
  attn_kernel<<<2048, 256, 0, stream>>>(qb, kb, vb, ab);
  gemm256<1, 4><<<256, 512, 0, stream>>>(ab, woutT, out, nullptr, nullptr, nullptr);
}